// Round 8
// baseline (266.473 us; speedup 1.0000x reference)
//
#include <hip/hip_runtime.h>
#include <hip/hip_bf16.h>

#define NUM_NODES 50000
#define NUM_EDGES 50000
#define NNZ       500000
#define D_IN      256
#define D_OUT     256
#define HB        128        // histogram blocks per array
#define HW4       12500      // 50000 keys / 4 per 32-bit word (u8 counts)
#define CHUNK     3907       // ceil(NNZ / HB)
#define NBLK      196        // ceil(50000 / 256) scan chunks

typedef __attribute__((ext_vector_type(8))) short  bf16x8;
typedef __attribute__((ext_vector_type(4))) float  f32x4;

// ---------- bf16 helpers ----------
static __device__ __forceinline__ float bf2f(unsigned short u) {
    return __uint_as_float(((unsigned)u) << 16);
}
static __device__ __forceinline__ unsigned short f2bf(float f) {
    unsigned u = __float_as_uint(f);
    u += 0x7FFFu + ((u >> 16) & 1u);   // RNE
    return (unsigned short)(u >> 16);
}

// ---------- 1. per-block LDS histograms (u8x4 packed) + folded W-transpose ----------
__global__ __launch_bounds__(256) void hist_kernel(
    const int* __restrict__ node_idx, const int* __restrict__ edge_idx,
    unsigned int* __restrict__ HbE, unsigned int* __restrict__ HbN,
    const float* __restrict__ W, unsigned short* __restrict__ Wt)
{
    const int arr = blockIdx.y;
    {
        int n = arr * HB + blockIdx.x;           // 0..255
        Wt[n * 256 + threadIdx.x] = f2bf(W[(size_t)threadIdx.x * 256 + n]);
    }
    const int* __restrict__ idx = arr ? node_idx : edge_idx;
    unsigned int* __restrict__ Hb = arr ? HbN : HbE;
    __shared__ unsigned int h[HW4];              // 50 KB -> 3 blocks/CU
    for (int i = threadIdx.x; i < HW4; i += 256) h[i] = 0;
    __syncthreads();
    int beg = blockIdx.x * CHUNK;
    int end = min(NNZ, beg + CHUNK);
    for (int i = beg + (int)threadIdx.x; i < end; i += 256) {
        int k = idx[i];
        atomicAdd(&h[k >> 2], 1u << ((k & 3) * 8));
    }
    __syncthreads();
    unsigned int* out = Hb + (size_t)blockIdx.x * HW4;
    for (int i = threadIdx.x; i < HW4; i += 256) out[i] = h[i];
}

// ---------- 2. fused hreduce + scan1 ----------
// grid (NBLK, 2). Block b owns keys [256b, 256b+256) = words [64b, 64b+64).
// Phase A (threads 0..63): column-reduce the 128 Hb rows, rewriting each row
// word as the cross-block exclusive prefix (u8x4). Totals -> LDS.
// Phase B (all 256): exclusive scan of the 256 key totals -> off[], bsums.
__global__ __launch_bounds__(256) void hredscan_kernel(
    unsigned int* __restrict__ HbE, unsigned int* __restrict__ HbN,
    int* __restrict__ offE, int* __restrict__ offN, int* __restrict__ bsums)
{
    const int arr = blockIdx.y;
    unsigned int* __restrict__ Hb = arr ? HbN : HbE;
    int* __restrict__ off = arr ? offN : offE;
    __shared__ int sh[256];
    const int tid = (int)threadIdx.x;
    const int b   = (int)blockIdx.x;

    if (tid < 64) {
        int w = b * 64 + tid;
        unsigned int s0 = 0, s1 = 0, s2 = 0, s3 = 0;
        if (w < HW4) {
            #pragma unroll 8
            for (int r = 0; r < HB; ++r) {
                unsigned int u = Hb[(size_t)r * HW4 + w];
                Hb[(size_t)r * HW4 + w] = s0 | (s1 << 8) | (s2 << 16) | (s3 << 24);
                s0 += u & 0xffu;
                s1 += (u >> 8) & 0xffu;
                s2 += (u >> 16) & 0xffu;
                s3 += (u >> 24) & 0xffu;
            }
        }
        sh[tid * 4]     = (int)s0;
        sh[tid * 4 + 1] = (int)s1;
        sh[tid * 4 + 2] = (int)s2;
        sh[tid * 4 + 3] = (int)s3;
    }
    __syncthreads();
    int v = sh[tid];
    __syncthreads();
    sh[tid] = v;
    __syncthreads();
    for (int s = 1; s < 256; s <<= 1) {
        int t = (tid >= s) ? sh[tid - s] : 0;
        __syncthreads();
        sh[tid] += t;
        __syncthreads();
    }
    int i = b * 256 + tid;
    if (i < 50000) off[i] = sh[tid] - v;           // chunk-local exclusive
    if (tid == 255) bsums[arr * NBLK + b] = sh[255];
}

// ---------- 3. scan stage 2 (tiny): scan chunk sums; off[50000] sentinels ----------
__global__ __launch_bounds__(256) void scan2_kernel(
    const int* __restrict__ bsums, int* __restrict__ bsum_off,
    int* __restrict__ offE, int* __restrict__ offN)
{
    __shared__ int sh[256];
    int tid = threadIdx.x;
    for (int arr = 0; arr < 2; ++arr) {
        int v = (tid < NBLK) ? bsums[arr * NBLK + tid] : 0;
        sh[tid] = v;
        __syncthreads();
        for (int s = 1; s < 256; s <<= 1) {
            int t = (tid >= s) ? sh[tid - s] : 0;
            __syncthreads();
            sh[tid] += t;
            __syncthreads();
        }
        if (tid < NBLK) bsum_off[arr * NBLK + tid] = sh[tid] - v;
        if (tid == NBLK - 1) {
            int* off = arr ? offN : offE;
            off[50000] = NNZ - (sh[tid] - v);      // off[50000]+bs[195]==NNZ
        }
        __syncthreads();
    }
}

// ---------- 4. atomic-free CSR fill (u8 cursors; bsum fused) ----------
__global__ __launch_bounds__(256) void fill_kernel(
    const int* __restrict__ node_idx, const int* __restrict__ edge_idx,
    const unsigned int* __restrict__ HbE, const unsigned int* __restrict__ HbN,
    const int* __restrict__ edge_off, const int* __restrict__ node_off,
    const int* __restrict__ bsum_off,
    int* __restrict__ edge_nodes, int* __restrict__ node_edges)
{
    const int arr = blockIdx.y;
    const int* __restrict__ key = arr ? node_idx : edge_idx;
    const int* __restrict__ val = arr ? edge_idx : node_idx;
    const unsigned int* __restrict__ Hb = arr ? HbN : HbE;
    const int* __restrict__ off = arr ? node_off : edge_off;
    const int* __restrict__ bs  = bsum_off + arr * NBLK;
    int* __restrict__ out       = arr ? node_edges : edge_nodes;

    __shared__ unsigned int h[HW4];              // 50 KB -> 3 blocks/CU
    const unsigned int* hrow = Hb + (size_t)blockIdx.x * HW4;
    for (int i = threadIdx.x; i < HW4; i += 256) h[i] = hrow[i];
    __syncthreads();

    int beg = blockIdx.x * CHUNK;
    int end = min(NNZ, beg + CHUNK);
    for (int i = beg + (int)threadIdx.x; i < end; i += 256) {
        int k = key[i];
        int sh = (k & 3) * 8;
        unsigned int old = atomicAdd(&h[k >> 2], 1u << sh);
        int rank = (int)((old >> sh) & 0xffu);
        out[off[k] + bs[k >> 8] + rank] = val[i];
    }
}

// ---------- 5. MFMA bf16 GEMM v2 (R5/R7-proven): xl = bf16(x) @ bf16(W) ----------
__global__ __launch_bounds__(256) void gemm_kernel(
    const float* __restrict__ x, const unsigned short* __restrict__ Wt,
    unsigned short* __restrict__ xl)
{
    __shared__ __align__(16) unsigned short sA[32 * 256];      // 16 KB
    __shared__ __align__(16) unsigned short sB[2][256 * 32];   // 32 KB

    const int tid  = threadIdx.x;
    const int l    = tid & 63;
    const int wq   = tid >> 6;
    const int quad = l >> 4;
    const int l15  = l & 15;
    const int m0   = blockIdx.x * 32;

    {
        int row = tid >> 3;
        int kb  = (tid & 7) * 32;
        int gm = m0 + row; if (gm > NUM_NODES - 1) gm = NUM_NODES - 1;
        const float* p = x + (size_t)gm * D_IN + kb;
        #pragma unroll
        for (int j = 0; j < 4; ++j) {
            float4 v0 = *(const float4*)(p + j * 8);
            float4 v1 = *(const float4*)(p + j * 8 + 4);
            bf16x8 av;
            av[0] = (short)f2bf(v0.x); av[1] = (short)f2bf(v0.y);
            av[2] = (short)f2bf(v0.z); av[3] = (short)f2bf(v0.w);
            av[4] = (short)f2bf(v1.x); av[5] = (short)f2bf(v1.y);
            av[6] = (short)f2bf(v1.z); av[7] = (short)f2bf(v1.w);
            int u  = (kb >> 3) + j;
            int us = u ^ (row & 7);
            *(bf16x8*)(&sA[row * 256 + us * 8]) = av;
        }
    }
    bf16x8 breg[4];
    #pragma unroll
    for (int i = 0; i < 4; ++i) {
        int c = i * 256 + tid, row = c >> 2, g = c & 3;
        breg[i] = *(const bf16x8*)(Wt + row * 256 + g * 8);
    }

    f32x4 acc[2][4];
    #pragma unroll
    for (int i = 0; i < 2; ++i)
        #pragma unroll
        for (int j = 0; j < 4; ++j) acc[i][j] = (f32x4){0.f, 0.f, 0.f, 0.f};

    int buf = 0;
    for (int k0 = 0; k0 < 8; ++k0) {
        #pragma unroll
        for (int i = 0; i < 4; ++i) {
            int c = i * 256 + tid, row = c >> 2, g = c & 3;
            int s = g ^ ((row >> 1) & 3);
            *(bf16x8*)(&sB[buf][row * 32 + s * 8]) = breg[i];
        }
        __syncthreads();
        if (k0 < 7) {
            #pragma unroll
            for (int i = 0; i < 4; ++i) {
                int c = i * 256 + tid, row = c >> 2, g = c & 3;
                breg[i] = *(const bf16x8*)(Wt + row * 256 + (k0 + 1) * 32 + g * 8);
            }
        }
        bf16x8 af[2];
        #pragma unroll
        for (int mi = 0; mi < 2; ++mi) {
            int r  = mi * 16 + l15;
            int us = (k0 * 4 + quad) ^ (r & 7);
            af[mi] = *(const bf16x8*)(&sA[r * 256 + us * 8]);
        }
        bf16x8 bfr[4];
        #pragma unroll
        for (int ni = 0; ni < 4; ++ni) {
            int r = wq * 64 + ni * 16 + l15;
            int s = quad ^ ((r >> 1) & 3);
            bfr[ni] = *(const bf16x8*)(&sB[buf][r * 32 + s * 8]);
        }
        #pragma unroll
        for (int mi = 0; mi < 2; ++mi)
            #pragma unroll
            for (int ni = 0; ni < 4; ++ni)
                acc[mi][ni] = __builtin_amdgcn_mfma_f32_16x16x32_bf16(
                    af[mi], bfr[ni], acc[mi][ni], 0, 0, 0);
        buf ^= 1;
    }

    float* bounce = (float*)&sB[0][0];
    for (int half = 0; half < 2; ++half) {
        __syncthreads();
        #pragma unroll
        for (int ni = 0; ni < 4; ++ni) {
            int col = wq * 64 + ni * 16 + l15;
            #pragma unroll
            for (int r = 0; r < 4; ++r)
                bounce[(quad * 4 + r) * 260 + col] = acc[half][ni][r];
        }
        __syncthreads();
        int row = tid >> 4;
        int c0  = (tid & 15) * 16;
        int gm  = m0 + half * 16 + row;
        if (gm < NUM_NODES) {
            const float* src = bounce + row * 260 + c0;
            bf16x8 o0, o1;
            #pragma unroll
            for (int j = 0; j < 8; ++j) o0[j] = (short)f2bf(src[j]);
            #pragma unroll
            for (int j = 0; j < 8; ++j) o1[j] = (short)f2bf(src[8 + j]);
            *(bf16x8*)(xl + (size_t)gm * D_OUT + c0)     = o0;
            *(bf16x8*)(xl + (size_t)gm * D_OUT + c0 + 8) = o1;
        }
    }
}

// ---------- 6. edge aggregation (feature-split x2, ILP-4) ----------
// grid (12500, 2): y = feature half (128 feats). Lane covers ushort2 (4 B);
// per-pass working set 12.8 MB for better per-XCD L2 reuse.
__global__ __launch_bounds__(256) void edge_agg_kernel(
    const unsigned short* __restrict__ xl,
    const int* __restrict__ edge_off, const int* __restrict__ bsE,
    const int* __restrict__ edge_nodes,
    unsigned short* __restrict__ e_feat)
{
    int e = blockIdx.x * 4 + (threadIdx.x >> 6);
    int lane = threadIdx.x & 63;
    int fo = blockIdx.y * 128 + lane * 2;        // feature offset
    if (e >= NUM_EDGES) return;
    int beg = edge_off[e]     + bsE[e >> 8];
    int end = edge_off[e + 1] + bsE[(e + 1) >> 8];
    float ax = 0.f, ay = 0.f;
    int j = beg;
    for (; j + 4 <= end; j += 4) {
        int n0 = edge_nodes[j];
        int n1 = edge_nodes[j + 1];
        int n2 = edge_nodes[j + 2];
        int n3 = edge_nodes[j + 3];
        ushort2 u0 = *(const ushort2*)(xl + (size_t)n0 * D_OUT + fo);
        ushort2 u1 = *(const ushort2*)(xl + (size_t)n1 * D_OUT + fo);
        ushort2 u2 = *(const ushort2*)(xl + (size_t)n2 * D_OUT + fo);
        ushort2 u3 = *(const ushort2*)(xl + (size_t)n3 * D_OUT + fo);
        ax += bf2f(u0.x) + bf2f(u1.x) + bf2f(u2.x) + bf2f(u3.x);
        ay += bf2f(u0.y) + bf2f(u1.y) + bf2f(u2.y) + bf2f(u3.y);
    }
    for (; j < end; ++j) {
        int node = edge_nodes[j];
        ushort2 u = *(const ushort2*)(xl + (size_t)node * D_OUT + fo);
        ax += bf2f(u.x); ay += bf2f(u.y);
    }
    float binv = (end > beg) ? 1.0f / (float)(end - beg) : 0.0f;
    ushort2 o;
    o.x = f2bf(ax * binv); o.y = f2bf(ay * binv);
    *(ushort2*)(e_feat + (size_t)e * D_OUT + fo) = o;
}

// ---------- 7. node aggregation (feature-split x2, Dv fused, ILP-4) ----------
__global__ __launch_bounds__(256) void node_agg_kernel(
    const unsigned short* __restrict__ e_feat,
    const int* __restrict__ node_off, const int* __restrict__ bsN,
    const int* __restrict__ node_edges,
    const float* __restrict__ w, const float* __restrict__ bias,
    float* __restrict__ out)
{
    int n = blockIdx.x * 4 + (threadIdx.x >> 6);
    int lane = threadIdx.x & 63;
    int fo = blockIdx.y * 128 + lane * 2;
    if (n >= NUM_NODES) return;
    int beg = node_off[n]     + bsN[n >> 8];
    int end = node_off[n + 1] + bsN[(n + 1) >> 8];
    float ax = 0.f, ay = 0.f;
    float dsum = 0.f;
    int j = beg;
    for (; j + 4 <= end; j += 4) {
        int e0 = node_edges[j];
        int e1 = node_edges[j + 1];
        int e2 = node_edges[j + 2];
        int e3 = node_edges[j + 3];
        ushort2 u0 = *(const ushort2*)(e_feat + (size_t)e0 * D_OUT + fo);
        ushort2 u1 = *(const ushort2*)(e_feat + (size_t)e1 * D_OUT + fo);
        ushort2 u2 = *(const ushort2*)(e_feat + (size_t)e2 * D_OUT + fo);
        ushort2 u3 = *(const ushort2*)(e_feat + (size_t)e3 * D_OUT + fo);
        dsum += w[e0] + w[e1] + w[e2] + w[e3];
        ax += bf2f(u0.x) + bf2f(u1.x) + bf2f(u2.x) + bf2f(u3.x);
        ay += bf2f(u0.y) + bf2f(u1.y) + bf2f(u2.y) + bf2f(u3.y);
    }
    for (; j < end; ++j) {
        int e = node_edges[j];
        dsum += w[e];
        ushort2 u = *(const ushort2*)(e_feat + (size_t)e * D_OUT + fo);
        ax += bf2f(u.x); ay += bf2f(u.y);
    }
    float dinv = (dsum > 0.0f) ? 1.0f / dsum : 0.0f;
    float2 bv = *(const float2*)(bias + fo);
    float2 o;
    o.x = ax * dinv + bv.x;
    o.y = ay * dinv + bv.y;
    *(float2*)(out + (size_t)n * D_OUT + fo) = o;
}

extern "C" void kernel_launch(void* const* d_in, const int* in_sizes, int n_in,
                              void* d_out, int out_size, void* d_ws, size_t ws_size,
                              hipStream_t stream) {
    const float* x    = (const float*)d_in[0];
    const int*   hidx = (const int*)d_in[1];     // [2, NNZ]: row0=node_idx, row1=edge_idx
    const float* w    = (const float*)d_in[2];
    const float* W    = (const float*)d_in[3];
    const float* b    = (const float*)d_in[4];
    const int* node_idx = hidx;
    const int* edge_idx = hidx + NNZ;

    // ---- workspace carve-up ----
    char* ws = (char*)d_ws;
    size_t off = 0;
    auto alloc = [&](size_t bytes) -> void* {
        off = (off + 511) & ~(size_t)511;
        void* p = ws + off;
        off += bytes;
        return p;
    };
    unsigned short* xl     = (unsigned short*)alloc((size_t)NUM_NODES * D_OUT * 2); // 25.6 MB
    unsigned short* e_feat = (unsigned short*)alloc((size_t)NUM_EDGES * D_OUT * 2); // 25.6 MB
    int* edge_off   = (int*)alloc((NUM_EDGES + 1) * sizeof(int));
    int* node_off   = (int*)alloc((NUM_NODES + 1) * sizeof(int));
    int* edge_nodes = (int*)alloc((size_t)NNZ * sizeof(int));
    int* node_edges = (int*)alloc((size_t)NNZ * sizeof(int));
    unsigned short* Wt = (unsigned short*)alloc(256 * 256 * 2);
    int* bsums    = (int*)alloc(2 * NBLK * sizeof(int));
    int* bsum_off = (int*)alloc(2 * NBLK * sizeof(int));

    // Histogram/prefix scratch ALIASED over xl / e_feat (6.4 MB each; fully
    // consumed by fill_kernel before gemm/edge_agg write xl/e_feat).
    unsigned int* HbE = (unsigned int*)xl;
    unsigned int* HbN = (unsigned int*)e_feat;

    hist_kernel<<<dim3(HB, 2), 256, 0, stream>>>(node_idx, edge_idx, HbE, HbN, W, Wt);
    hredscan_kernel<<<dim3(NBLK, 2), 256, 0, stream>>>(HbE, HbN, edge_off, node_off, bsums);
    scan2_kernel<<<1, 256, 0, stream>>>(bsums, bsum_off, edge_off, node_off);
    fill_kernel<<<dim3(HB, 2), 256, 0, stream>>>(node_idx, edge_idx, HbE, HbN,
                                                 edge_off, node_off, bsum_off,
                                                 edge_nodes, node_edges);
    gemm_kernel<<<(NUM_NODES + 31) / 32, 256, 0, stream>>>(x, Wt, xl);
    edge_agg_kernel<<<dim3(NUM_EDGES / 4, 2), 256, 0, stream>>>(xl, edge_off, bsum_off,
                                                                edge_nodes, e_feat);
    node_agg_kernel<<<dim3(NUM_NODES / 4, 2), 256, 0, stream>>>(e_feat, node_off,
                                                                bsum_off + NBLK,
                                                                node_edges, w, b,
                                                                (float*)d_out);
}

// Round 10
// 240.580 us; speedup vs baseline: 1.1076x; 1.1076x over previous
//
#include <hip/hip_runtime.h>
#include <hip/hip_bf16.h>

#define NUM_NODES 50000
#define NUM_EDGES 50000
#define NNZ       500000
#define D_IN      256
#define D_OUT     256
#define HB        128        // histogram blocks per array (R8-proven)
#define HW4       12500      // 50000 keys / 4 per 32-bit word (u8 counts)
#define CHUNK     3907       // ceil(NNZ / HB)
#define NBLK      196        // ceil(50000 / 256) scan chunks

typedef __attribute__((ext_vector_type(8))) short  bf16x8;
typedef __attribute__((ext_vector_type(4))) float  f32x4;

// ---------- bf16 helpers ----------
static __device__ __forceinline__ float bf2f(unsigned short u) {
    return __uint_as_float(((unsigned)u) << 16);
}
static __device__ __forceinline__ unsigned short f2bf(float f) {
    unsigned u = __float_as_uint(f);
    u += 0x7FFFu + ((u >> 16) & 1u);   // RNE
    return (unsigned short)(u >> 16);
}

// ---------- 1. per-block LDS histograms (u8x4 packed) + folded W-transpose ----------
// R8-proven form: scalar copies, one W column per block.
__global__ __launch_bounds__(256) void hist_kernel(
    const int* __restrict__ node_idx, const int* __restrict__ edge_idx,
    unsigned int* __restrict__ HbE, unsigned int* __restrict__ HbN,
    const float* __restrict__ W, unsigned short* __restrict__ Wt)
{
    const int arr = blockIdx.y;
    {
        int n = arr * HB + blockIdx.x;           // 0..255
        Wt[n * 256 + threadIdx.x] = f2bf(W[(size_t)threadIdx.x * 256 + n]);
    }
    const int* __restrict__ idx = arr ? node_idx : edge_idx;
    unsigned int* __restrict__ Hb = arr ? HbN : HbE;
    __shared__ unsigned int h[HW4];              // 50 KB -> 3 blocks/CU
    for (int i = threadIdx.x; i < HW4; i += 256) h[i] = 0;
    __syncthreads();
    int beg = blockIdx.x * CHUNK;
    int end = min(NNZ, beg + CHUNK);
    for (int i = beg + (int)threadIdx.x; i < end; i += 256) {
        int k = idx[i];
        atomicAdd(&h[k >> 2], 1u << ((k & 3) * 8));
    }
    __syncthreads();
    unsigned int* out = Hb + (size_t)blockIdx.x * HW4;
    for (int i = threadIdx.x; i < HW4; i += 256) out[i] = h[i];
}

// ---------- 2. fused hreduce + scan1 (R8-proven) ----------
__global__ __launch_bounds__(256) void hredscan_kernel(
    unsigned int* __restrict__ HbE, unsigned int* __restrict__ HbN,
    int* __restrict__ offE, int* __restrict__ offN, int* __restrict__ bsums)
{
    const int arr = blockIdx.y;
    unsigned int* __restrict__ Hb = arr ? HbN : HbE;
    int* __restrict__ off = arr ? offN : offE;
    __shared__ int sh[256];
    const int tid = (int)threadIdx.x;
    const int b   = (int)blockIdx.x;

    if (tid < 64) {
        int w = b * 64 + tid;
        unsigned int s0 = 0, s1 = 0, s2 = 0, s3 = 0;
        if (w < HW4) {
            #pragma unroll 8
            for (int r = 0; r < HB; ++r) {
                unsigned int u = Hb[(size_t)r * HW4 + w];
                Hb[(size_t)r * HW4 + w] = s0 | (s1 << 8) | (s2 << 16) | (s3 << 24);
                s0 += u & 0xffu;
                s1 += (u >> 8) & 0xffu;
                s2 += (u >> 16) & 0xffu;
                s3 += (u >> 24) & 0xffu;
            }
        }
        sh[tid * 4]     = (int)s0;
        sh[tid * 4 + 1] = (int)s1;
        sh[tid * 4 + 2] = (int)s2;
        sh[tid * 4 + 3] = (int)s3;
    }
    __syncthreads();
    int v = sh[tid];
    __syncthreads();
    sh[tid] = v;
    __syncthreads();
    for (int s = 1; s < 256; s <<= 1) {
        int t = (tid >= s) ? sh[tid - s] : 0;
        __syncthreads();
        sh[tid] += t;
        __syncthreads();
    }
    int i = b * 256 + tid;
    if (i < 50000) off[i] = sh[tid] - v;           // chunk-local exclusive
    if (tid == 255) bsums[arr * NBLK + b] = sh[255];
}

// ---------- 3. scan stage 2: scan chunk sums; off[50000] sentinels ----------
__global__ __launch_bounds__(256) void scan2_kernel(
    const int* __restrict__ bsums, int* __restrict__ bsum_off,
    int* __restrict__ offE, int* __restrict__ offN)
{
    __shared__ int sh[256];
    int tid = threadIdx.x;
    for (int arr = 0; arr < 2; ++arr) {
        int v = (tid < NBLK) ? bsums[arr * NBLK + tid] : 0;
        sh[tid] = v;
        __syncthreads();
        for (int s = 1; s < 256; s <<= 1) {
            int t = (tid >= s) ? sh[tid - s] : 0;
            __syncthreads();
            sh[tid] += t;
            __syncthreads();
        }
        if (tid < NBLK) bsum_off[arr * NBLK + tid] = sh[tid] - v;
        if (tid == NBLK - 1) {
            int* off = arr ? offN : offE;
            off[50000] = NNZ - (sh[tid] - v);      // off[50000]+bs[195]==NNZ
        }
        __syncthreads();
    }
}

// ---------- 4. atomic-free CSR fill (u8 cursors; bsum fused; R8-proven) ----------
__global__ __launch_bounds__(256) void fill_kernel(
    const int* __restrict__ node_idx, const int* __restrict__ edge_idx,
    const unsigned int* __restrict__ HbE, const unsigned int* __restrict__ HbN,
    const int* __restrict__ edge_off, const int* __restrict__ node_off,
    const int* __restrict__ bsum_off,
    int* __restrict__ edge_nodes, int* __restrict__ node_edges)
{
    const int arr = blockIdx.y;
    const int* __restrict__ key = arr ? node_idx : edge_idx;
    const int* __restrict__ val = arr ? edge_idx : node_idx;
    const unsigned int* __restrict__ Hb = arr ? HbN : HbE;
    const int* __restrict__ off = arr ? node_off : edge_off;
    const int* __restrict__ bs  = bsum_off + arr * NBLK;
    int* __restrict__ out       = arr ? node_edges : edge_nodes;

    __shared__ unsigned int h[HW4];              // 50 KB -> 3 blocks/CU
    const unsigned int* hrow = Hb + (size_t)blockIdx.x * HW4;
    for (int i = threadIdx.x; i < HW4; i += 256) h[i] = hrow[i];
    __syncthreads();

    int beg = blockIdx.x * CHUNK;
    int end = min(NNZ, beg + CHUNK);
    for (int i = beg + (int)threadIdx.x; i < end; i += 256) {
        int k = key[i];
        int sh = (k & 3) * 8;
        unsigned int old = atomicAdd(&h[k >> 2], 1u << sh);
        int rank = (int)((old >> sh) & 0xffu);
        out[off[k] + bs[k >> 8] + rank] = val[i];
    }
}

// ---------- 5. MFMA bf16 GEMM v2 (R5/R7/R8-proven): xl = bf16(x) @ bf16(W) ----------
__global__ __launch_bounds__(256) void gemm_kernel(
    const float* __restrict__ x, const unsigned short* __restrict__ Wt,
    unsigned short* __restrict__ xl)
{
    __shared__ __align__(16) unsigned short sA[32 * 256];      // 16 KB
    __shared__ __align__(16) unsigned short sB[2][256 * 32];   // 32 KB

    const int tid  = threadIdx.x;
    const int l    = tid & 63;
    const int wq   = tid >> 6;
    const int quad = l >> 4;
    const int l15  = l & 15;
    const int m0   = blockIdx.x * 32;

    {
        int row = tid >> 3;
        int kb  = (tid & 7) * 32;
        int gm = m0 + row; if (gm > NUM_NODES - 1) gm = NUM_NODES - 1;
        const float* p = x + (size_t)gm * D_IN + kb;
        #pragma unroll
        for (int j = 0; j < 4; ++j) {
            float4 v0 = *(const float4*)(p + j * 8);
            float4 v1 = *(const float4*)(p + j * 8 + 4);
            bf16x8 av;
            av[0] = (short)f2bf(v0.x); av[1] = (short)f2bf(v0.y);
            av[2] = (short)f2bf(v0.z); av[3] = (short)f2bf(v0.w);
            av[4] = (short)f2bf(v1.x); av[5] = (short)f2bf(v1.y);
            av[6] = (short)f2bf(v1.z); av[7] = (short)f2bf(v1.w);
            int u  = (kb >> 3) + j;
            int us = u ^ (row & 7);
            *(bf16x8*)(&sA[row * 256 + us * 8]) = av;
        }
    }
    bf16x8 breg[4];
    #pragma unroll
    for (int i = 0; i < 4; ++i) {
        int c = i * 256 + tid, row = c >> 2, g = c & 3;
        breg[i] = *(const bf16x8*)(Wt + row * 256 + g * 8);
    }

    f32x4 acc[2][4];
    #pragma unroll
    for (int i = 0; i < 2; ++i)
        #pragma unroll
        for (int j = 0; j < 4; ++j) acc[i][j] = (f32x4){0.f, 0.f, 0.f, 0.f};

    int buf = 0;
    for (int k0 = 0; k0 < 8; ++k0) {
        #pragma unroll
        for (int i = 0; i < 4; ++i) {
            int c = i * 256 + tid, row = c >> 2, g = c & 3;
            int s = g ^ ((row >> 1) & 3);
            *(bf16x8*)(&sB[buf][row * 32 + s * 8]) = breg[i];
        }
        __syncthreads();
        if (k0 < 7) {
            #pragma unroll
            for (int i = 0; i < 4; ++i) {
                int c = i * 256 + tid, row = c >> 2, g = c & 3;
                breg[i] = *(const bf16x8*)(Wt + row * 256 + (k0 + 1) * 32 + g * 8);
            }
        }
        bf16x8 af[2];
        #pragma unroll
        for (int mi = 0; mi < 2; ++mi) {
            int r  = mi * 16 + l15;
            int us = (k0 * 4 + quad) ^ (r & 7);
            af[mi] = *(const bf16x8*)(&sA[r * 256 + us * 8]);
        }
        bf16x8 bfr[4];
        #pragma unroll
        for (int ni = 0; ni < 4; ++ni) {
            int r = wq * 64 + ni * 16 + l15;
            int s = quad ^ ((r >> 1) & 3);
            bfr[ni] = *(const bf16x8*)(&sB[buf][r * 32 + s * 8]);
        }
        #pragma unroll
        for (int mi = 0; mi < 2; ++mi)
            #pragma unroll
            for (int ni = 0; ni < 4; ++ni)
                acc[mi][ni] = __builtin_amdgcn_mfma_f32_16x16x32_bf16(
                    af[mi], bfr[ni], acc[mi][ni], 0, 0, 0);
        buf ^= 1;
    }

    float* bounce = (float*)&sB[0][0];
    for (int half = 0; half < 2; ++half) {
        __syncthreads();
        #pragma unroll
        for (int ni = 0; ni < 4; ++ni) {
            int col = wq * 64 + ni * 16 + l15;
            #pragma unroll
            for (int r = 0; r < 4; ++r)
                bounce[(quad * 4 + r) * 260 + col] = acc[half][ni][r];
        }
        __syncthreads();
        int row = tid >> 4;
        int c0  = (tid & 15) * 16;
        int gm  = m0 + half * 16 + row;
        if (gm < NUM_NODES) {
            const float* src = bounce + row * 260 + c0;
            bf16x8 o0, o1;
            #pragma unroll
            for (int j = 0; j < 8; ++j) o0[j] = (short)f2bf(src[j]);
            #pragma unroll
            for (int j = 0; j < 8; ++j) o1[j] = (short)f2bf(src[8 + j]);
            *(bf16x8*)(xl + (size_t)gm * D_OUT + c0)     = o0;
            *(bf16x8*)(xl + (size_t)gm * D_OUT + c0 + 8) = o1;
        }
    }
}

// ---------- 6. edge aggregation (R7-proven: full row ushort4, ILP-4) ----------
__global__ __launch_bounds__(256) void edge_agg_kernel(
    const unsigned short* __restrict__ xl,
    const int* __restrict__ edge_off, const int* __restrict__ bsE,
    const int* __restrict__ edge_nodes,
    unsigned short* __restrict__ e_feat)
{
    int e = blockIdx.x * 4 + (threadIdx.x >> 6);
    int lane = threadIdx.x & 63;
    if (e >= NUM_EDGES) return;
    int beg = edge_off[e]     + bsE[e >> 8];
    int end = edge_off[e + 1] + bsE[(e + 1) >> 8];
    float ax = 0.f, ay = 0.f, az = 0.f, aw = 0.f;
    int j = beg;
    for (; j + 4 <= end; j += 4) {
        int n0 = edge_nodes[j];
        int n1 = edge_nodes[j + 1];
        int n2 = edge_nodes[j + 2];
        int n3 = edge_nodes[j + 3];
        ushort4 u0 = *(const ushort4*)(xl + (size_t)n0 * D_OUT + lane * 4);
        ushort4 u1 = *(const ushort4*)(xl + (size_t)n1 * D_OUT + lane * 4);
        ushort4 u2 = *(const ushort4*)(xl + (size_t)n2 * D_OUT + lane * 4);
        ushort4 u3 = *(const ushort4*)(xl + (size_t)n3 * D_OUT + lane * 4);
        ax += bf2f(u0.x) + bf2f(u1.x) + bf2f(u2.x) + bf2f(u3.x);
        ay += bf2f(u0.y) + bf2f(u1.y) + bf2f(u2.y) + bf2f(u3.y);
        az += bf2f(u0.z) + bf2f(u1.z) + bf2f(u2.z) + bf2f(u3.z);
        aw += bf2f(u0.w) + bf2f(u1.w) + bf2f(u2.w) + bf2f(u3.w);
    }
    for (; j < end; ++j) {
        int node = edge_nodes[j];
        ushort4 u = *(const ushort4*)(xl + (size_t)node * D_OUT + lane * 4);
        ax += bf2f(u.x); ay += bf2f(u.y); az += bf2f(u.z); aw += bf2f(u.w);
    }
    float binv = (end > beg) ? 1.0f / (float)(end - beg) : 0.0f;
    ushort4 o;
    o.x = f2bf(ax * binv); o.y = f2bf(ay * binv);
    o.z = f2bf(az * binv); o.w = f2bf(aw * binv);
    *(ushort4*)(e_feat + (size_t)e * D_OUT + lane * 4) = o;
}

// ---------- 7. node aggregation (R7-proven: full row, ILP-4, Dv fused) ----------
__global__ __launch_bounds__(256) void node_agg_kernel(
    const unsigned short* __restrict__ e_feat,
    const int* __restrict__ node_off, const int* __restrict__ bsN,
    const int* __restrict__ node_edges,
    const float* __restrict__ w, const float* __restrict__ bias,
    float* __restrict__ out)
{
    int n = blockIdx.x * 4 + (threadIdx.x >> 6);
    int lane = threadIdx.x & 63;
    if (n >= NUM_NODES) return;
    int beg = node_off[n]     + bsN[n >> 8];
    int end = node_off[n + 1] + bsN[(n + 1) >> 8];
    float ax = 0.f, ay = 0.f, az = 0.f, aw = 0.f;
    float dsum = 0.f;
    int j = beg;
    for (; j + 4 <= end; j += 4) {
        int e0 = node_edges[j];
        int e1 = node_edges[j + 1];
        int e2 = node_edges[j + 2];
        int e3 = node_edges[j + 3];
        ushort4 u0 = *(const ushort4*)(e_feat + (size_t)e0 * D_OUT + lane * 4);
        ushort4 u1 = *(const ushort4*)(e_feat + (size_t)e1 * D_OUT + lane * 4);
        ushort4 u2 = *(const ushort4*)(e_feat + (size_t)e2 * D_OUT + lane * 4);
        ushort4 u3 = *(const ushort4*)(e_feat + (size_t)e3 * D_OUT + lane * 4);
        dsum += w[e0] + w[e1] + w[e2] + w[e3];
        ax += bf2f(u0.x) + bf2f(u1.x) + bf2f(u2.x) + bf2f(u3.x);
        ay += bf2f(u0.y) + bf2f(u1.y) + bf2f(u2.y) + bf2f(u3.y);
        az += bf2f(u0.z) + bf2f(u1.z) + bf2f(u2.z) + bf2f(u3.z);
        aw += bf2f(u0.w) + bf2f(u1.w) + bf2f(u2.w) + bf2f(u3.w);
    }
    for (; j < end; ++j) {
        int e = node_edges[j];
        dsum += w[e];
        ushort4 u = *(const ushort4*)(e_feat + (size_t)e * D_OUT + lane * 4);
        ax += bf2f(u.x); ay += bf2f(u.y); az += bf2f(u.z); aw += bf2f(u.w);
    }
    float dinv = (dsum > 0.0f) ? 1.0f / dsum : 0.0f;
    float4 bv = *(const float4*)(bias + lane * 4);
    float4 o;
    o.x = ax * dinv + bv.x;
    o.y = ay * dinv + bv.y;
    o.z = az * dinv + bv.z;
    o.w = aw * dinv + bv.w;
    *(float4*)(out + (size_t)n * D_OUT + lane * 4) = o;
}

extern "C" void kernel_launch(void* const* d_in, const int* in_sizes, int n_in,
                              void* d_out, int out_size, void* d_ws, size_t ws_size,
                              hipStream_t stream) {
    const float* x    = (const float*)d_in[0];
    const int*   hidx = (const int*)d_in[1];     // [2, NNZ]: row0=node_idx, row1=edge_idx
    const float* w    = (const float*)d_in[2];
    const float* W    = (const float*)d_in[3];
    const float* b    = (const float*)d_in[4];
    const int* node_idx = hidx;
    const int* edge_idx = hidx + NNZ;

    // ---- workspace carve-up ----
    char* ws = (char*)d_ws;
    size_t off = 0;
    auto alloc = [&](size_t bytes) -> void* {
        off = (off + 511) & ~(size_t)511;
        void* p = ws + off;
        off += bytes;
        return p;
    };
    unsigned short* xl     = (unsigned short*)alloc((size_t)NUM_NODES * D_OUT * 2); // 25.6 MB
    unsigned short* e_feat = (unsigned short*)alloc((size_t)NUM_EDGES * D_OUT * 2); // 25.6 MB
    int* edge_off   = (int*)alloc((NUM_EDGES + 1) * sizeof(int));
    int* node_off   = (int*)alloc((NUM_NODES + 1) * sizeof(int));
    int* edge_nodes = (int*)alloc((size_t)NNZ * sizeof(int));
    int* node_edges = (int*)alloc((size_t)NNZ * sizeof(int));
    unsigned short* Wt = (unsigned short*)alloc(256 * 256 * 2);
    int* bsums    = (int*)alloc(2 * NBLK * sizeof(int));
    int* bsum_off = (int*)alloc(2 * NBLK * sizeof(int));

    // Histogram/prefix scratch ALIASED over xl / e_feat (6.4 MB each; fully
    // consumed by fill_kernel before gemm/edge_agg write xl/e_feat).
    unsigned int* HbE = (unsigned int*)xl;
    unsigned int* HbN = (unsigned int*)e_feat;

    hist_kernel<<<dim3(HB, 2), 256, 0, stream>>>(node_idx, edge_idx, HbE, HbN, W, Wt);
    hredscan_kernel<<<dim3(NBLK, 2), 256, 0, stream>>>(HbE, HbN, edge_off, node_off, bsums);
    scan2_kernel<<<1, 256, 0, stream>>>(bsums, bsum_off, edge_off, node_off);
    fill_kernel<<<dim3(HB, 2), 256, 0, stream>>>(node_idx, edge_idx, HbE, HbN,
                                                 edge_off, node_off, bsum_off,
                                                 edge_nodes, node_edges);
    gemm_kernel<<<(NUM_NODES + 31) / 32, 256, 0, stream>>>(x, Wt, xl);
    edge_agg_kernel<<<NUM_EDGES / 4, 256, 0, stream>>>(xl, edge_off, bsum_off,
                                                       edge_nodes, e_feat);
    node_agg_kernel<<<NUM_NODES / 4, 256, 0, stream>>>(e_feat, node_off, bsum_off + NBLK,
                                                       node_edges, w, b, (float*)d_out);
}